// Round 16
// baseline (159.624 us; speedup 1.0000x reference)
//
#include <hip/hip_runtime.h>

#define BATCH 4096
#define DIM   128
#define NT    32   // 4096 / 128 tiles per dimension
#define REPS  10   // probe: K2 body looped; reps 0..8 -> scratch sinks
// TEMP = 0.25 -> 1/T = 4; 4*log2(e):
#define EXP_SCALE 5.770780163555854f

typedef __bf16 bf16_t;
typedef __bf16 bf16x8 __attribute__((ext_vector_type(8)));
typedef float  f32x4  __attribute__((ext_vector_type(4)));

// raw 2^x: input range here is |x| <= 5.8 -> no denormal/overflow guards
// needed; bypasses any OCML exp2f wrapper sequence.
__device__ __forceinline__ float exp2_raw(float x) {
    float r;
    asm("v_exp_f32 %0, %1" : "=v"(r) : "v"(x));
    return r;
}

// ---------------------------------------------------------------------------
// MEASUREMENT ROUND 3 (+1 safe fix): R15 pipeline (best, 73.8us) with K2's
// body looped REPS=10 in one dispatch (reps 0..8 -> scratch atomics, rep 9
// -> real denoms; bitwise-identical final state, pattern proven in R13/R14
// probes). Purpose: R15's 16-wave/CU K2 was never profiled; R14's profile
// (8 waves) showed VALUBusy 45.8 / MfmaUtil 14.2 / HBM 3 -- nothing
// saturated. Discriminate: VALUBusy>=75 at 16 waves => VALU-op-bound (fix:
// cut ops); ~46-55 => latency floor (done). The single in-probe change:
// exp2f -> raw v_exp_f32 (OCML wrapper removal); dur delta quantifies it.
// ---------------------------------------------------------------------------

// ---------------------------------------------------------------------------
// Kernel A: per row k, normalize emb_i[k] and emb_j[k] (fp32), write bf16
// z_i, z_j, pos[k]. Blocks 0..7 zero the denom region (32 KB). (R8 body.)
// ---------------------------------------------------------------------------
__global__ __launch_bounds__(256) void normalize_kernel(
    const float* __restrict__ emb_i, const float* __restrict__ emb_j,
    bf16_t* __restrict__ zi, bf16_t* __restrict__ zj, float* __restrict__ pos,
    float* __restrict__ denoms /* rowDenom(4096) ++ colDenom(4096) */)
{
    if (blockIdx.x < 8) {
        int idx = (blockIdx.x * 256 + threadIdx.x) * 4;
        *(float4*)&denoms[idx] = make_float4(0.f, 0.f, 0.f, 0.f);
    }

    int wave = threadIdx.x >> 6;
    int lane = threadIdx.x & 63;
    int k = blockIdx.x * 4 + wave;

    const float2* ei = (const float2*)(emb_i + (size_t)k * DIM);
    const float2* ej = (const float2*)(emb_j + (size_t)k * DIM);
    float2 a = ei[lane];
    float2 b = ej[lane];

    float sii = a.x * a.x + a.y * a.y;
    float sjj = b.x * b.x + b.y * b.y;
    float sij = a.x * b.x + a.y * b.y;
#pragma unroll
    for (int m = 1; m < 64; m <<= 1) {
        sii += __shfl_xor(sii, m);
        sjj += __shfl_xor(sjj, m);
        sij += __shfl_xor(sij, m);
    }
    float inv_i = 1.0f / fmaxf(sqrtf(sii), 1e-12f);
    float inv_j = 1.0f / fmaxf(sqrtf(sjj), 1e-12f);

    struct bf16_2 { bf16_t x, y; };
    bf16_2 pi, pj;
    pi.x = (bf16_t)(a.x * inv_i);  pi.y = (bf16_t)(a.y * inv_i);
    pj.x = (bf16_t)(b.x * inv_j);  pj.y = (bf16_t)(b.y * inv_j);
    ((bf16_2*)(zi + (size_t)k * DIM))[lane] = pi;
    ((bf16_2*)(zj + (size_t)k * DIM))[lane] = pj;

    if (lane == 0) pos[k] = sij * inv_i * inv_j;
}

// ---------------------------------------------------------------------------
// Kernel B: R15's best body (128x128 tile, 512 thr = 8 waves in 4x2 grid,
// each wave 32x64 out, acc[2][4]; launch_bounds(512,4) -> 128 VGPR cap,
// no spill at ~110 needed; padded-136 LDS rows) wrapped in the REPS loop.
// exp via raw v_exp_f32.
// ---------------------------------------------------------------------------
__global__ __launch_bounds__(512, 4) void gemm_exp_kernel(
    const bf16_t* __restrict__ zi, const bf16_t* __restrict__ zj,
    float* __restrict__ rowDenom, float* __restrict__ colDenom,
    float* __restrict__ scratchR, float* __restrict__ scratchC)
{
    __shared__ __align__(16) bf16_t zi_s[128][136];
    __shared__ __align__(16) bf16_t zj_s[128][136];
    __shared__ float rowRed[2][128];
    __shared__ float colRed[4][128];

    const int tid = threadIdx.x;
    const int ti = blockIdx.x, tj = blockIdx.y;

    const int wave = tid >> 6;
    const int lane = tid & 63;
    const int l15  = lane & 15;
    const int quad = lane >> 4;
    const int wr   = wave >> 1;   // 0..3 : 32-row group
    const int wc   = wave & 1;    // 0..1 : 64-col group

#pragma unroll 1
    for (int rep = 0; rep < REPS; ++rep) {
        float* rD = (rep == REPS - 1) ? rowDenom : scratchR;
        float* cD = (rep == REPS - 1) ? colDenom : scratchC;

        // Stage 128x128 bf16 of each matrix: 2048 16B-chunks, 4 iters.
#pragma unroll
        for (int it = 0; it < 4; ++it) {
            int c = it * 512 + tid;
            int row = c >> 4;          // 16 chunks per row
            int col = (c & 15) << 3;   // 8 bf16 per chunk
            *(uint4*)&zi_s[row][col] =
                *(const uint4*)(zi + ((size_t)(ti * 128 + row)) * DIM + col);
            *(uint4*)&zj_s[row][col] =
                *(const uint4*)(zj + ((size_t)(tj * 128 + row)) * DIM + col);
        }
        __syncthreads();

        const f32x4 vzero = {0.f, 0.f, 0.f, 0.f};
        f32x4 acc[2][4];
#pragma unroll
        for (int mr = 0; mr < 2; ++mr)
#pragma unroll
            for (int nc = 0; nc < 4; ++nc) acc[mr][nc] = vzero;

#pragma unroll
        for (int ks = 0; ks < 4; ++ks) {
            int k0 = ks * 32 + quad * 8;
            bf16x8 afrag[2], bfrag[4];
#pragma unroll
            for (int mr = 0; mr < 2; ++mr)
                afrag[mr] = *(const bf16x8*)&zi_s[wr * 32 + mr * 16 + l15][k0];
#pragma unroll
            for (int nc = 0; nc < 4; ++nc)
                bfrag[nc] = *(const bf16x8*)&zj_s[wc * 64 + nc * 16 + l15][k0];
#pragma unroll
            for (int mr = 0; mr < 2; ++mr)
#pragma unroll
                for (int nc = 0; nc < 4; ++nc)
                    acc[mr][nc] = __builtin_amdgcn_mfma_f32_16x16x32_bf16(
                        afrag[mr], bfrag[nc], acc[mr][nc], 0, 0, 0);
        }

        // Epilogue: exp and partial sums.
        float rowPart[2][4] = {{0.f, 0.f, 0.f, 0.f}, {0.f, 0.f, 0.f, 0.f}};
        float colPart[4]    = {0.f, 0.f, 0.f, 0.f};
#pragma unroll
        for (int mr = 0; mr < 2; ++mr)
#pragma unroll
            for (int nc = 0; nc < 4; ++nc)
#pragma unroll
                for (int r = 0; r < 4; ++r) {
                    float e = exp2_raw(acc[mr][nc][r] * EXP_SCALE);
                    rowPart[mr][r] += e;   // row = wr*32 + mr*16 + quad*4 + r
                    colPart[nc]    += e;   // col = wc*64 + nc*16 + l15
                }

        // Row sums: 16-lane shfl, cross-wave (2 wc-groups) via LDS.
#pragma unroll
        for (int mr = 0; mr < 2; ++mr)
#pragma unroll
            for (int r = 0; r < 4; ++r) {
                float v = rowPart[mr][r];
                v += __shfl_xor(v, 1);
                v += __shfl_xor(v, 2);
                v += __shfl_xor(v, 4);
                v += __shfl_xor(v, 8);
                if (l15 == 0)
                    rowRed[wc][wr * 32 + mr * 16 + quad * 4 + r] = v;
            }

        // Col sums: quad shfl-reduce, cross-wave (4 wr-groups) via LDS.
#pragma unroll
        for (int nc = 0; nc < 4; ++nc) {
            float v = colPart[nc];
            v += __shfl_xor(v, 16);
            v += __shfl_xor(v, 32);
            if (quad == 0) colRed[wr][wc * 64 + nc * 16 + l15] = v;
        }
        __syncthreads();

        if (tid < 128) {
            float rs = rowRed[0][tid] + rowRed[1][tid];
            atomicAdd(&rD[ti * 128 + tid], rs);
        } else if (tid < 256) {
            int c = tid - 128;
            float cs = colRed[0][c] + colRed[1][c] + colRed[2][c] + colRed[3][c];
            atomicAdd(&cD[tj * 128 + c], cs);
        }
        // Next rep's staging touches only zi_s/zj_s (disjoint from
        // rowRed/colRed); the post-staging barrier orders colRed reuse.
    }
}

// ---------------------------------------------------------------------------
// Kernel C: 1 block x 1024 threads; 3 independent float4 loads per thread,
// 8 logf, wave shfl-reduce, 16-way LDS reduce (R8 version).
// ---------------------------------------------------------------------------
__global__ __launch_bounds__(1024) void finalize_kernel(
    const float* __restrict__ denoms, const float* __restrict__ pos,
    float* __restrict__ out)
{
    const float4* rowD4 = (const float4*)denoms;            // 1024 float4
    const float4* colD4 = (const float4*)(denoms + BATCH);  // 1024 float4
    const float4* pos4  = (const float4*)pos;               // 1024 float4

    const int tid  = threadIdx.x;
    const int lane = tid & 63;
    const int wv   = tid >> 6;

    float4 rd = rowD4[tid];
    float4 cd = colD4[tid];
    float4 p  = pos4[tid];

    float acc = logf(rd.x) + logf(rd.y) + logf(rd.z) + logf(rd.w)
              + logf(cd.x) + logf(cd.y) + logf(cd.z) + logf(cd.w)
              - 8.0f * (p.x + p.y + p.z + p.w);

#pragma unroll
    for (int m = 1; m < 64; m <<= 1) acc += __shfl_xor(acc, m);

    __shared__ float red[16];
    if (lane == 0) red[wv] = acc;
    __syncthreads();
    if (wv == 0) {
        float v = (lane < 16) ? red[lane] : 0.0f;
#pragma unroll
        for (int m = 1; m < 64; m <<= 1) v += __shfl_xor(v, m);
        if (lane == 0) out[0] = v * (1.0f / (2.0f * BATCH));
    }
}

extern "C" void kernel_launch(void* const* d_in, const int* in_sizes, int n_in,
                              void* d_out, int out_size, void* d_ws, size_t ws_size,
                              hipStream_t stream) {
    const float* emb_i = (const float*)d_in[0];
    const float* emb_j = (const float*)d_in[1];
    float* out = (float*)d_out;

    char* ws = (char*)d_ws;
    bf16_t* zi       = (bf16_t*)(ws);                 // 1 MB
    bf16_t* zj       = (bf16_t*)(ws + (1u << 20));    // 1 MB
    float*  denoms   = (float*)(ws + (2u << 20));     // 32 KB (row ++ col)
    float*  pos      = denoms + 2 * BATCH;            // 16 KB
    float*  scratchR = (float*)(ws + (4u << 20));     // 16 KB (probe sink)
    float*  scratchC = scratchR + BATCH;              // 16 KB (probe sink)

    normalize_kernel<<<BATCH / 4, 256, 0, stream>>>(emb_i, emb_j, zi, zj, pos, denoms);
    gemm_exp_kernel<<<dim3(NT, NT), 512, 0, stream>>>(zi, zj, denoms, denoms + BATCH,
                                                      scratchR, scratchC);
    finalize_kernel<<<1, 1024, 0, stream>>>(denoms, pos, out);
}

// Round 17
// 73.627 us; speedup vs baseline: 2.1680x; 2.1680x over previous
//
#include <hip/hip_runtime.h>

#define BATCH 4096
#define DIM   128
#define NT    32   // 4096 / 128 tiles per dimension
// TEMP = 0.25 -> 1/T = 4; 4*log2(e):
#define EXP_SCALE 5.770780163555854f

typedef __bf16 bf16_t;
typedef __bf16 bf16x8 __attribute__((ext_vector_type(8)));
typedef float  f32x4  __attribute__((ext_vector_type(4)));

// raw 2^x: input range here is |x| <= 5.8 (|s|<=1, scale 5.77) -> no
// denormal/overflow guards needed. R16 probe: replacing OCML exp2f with
// this cut K2 from 12.5 -> 11.2 us/rep.
__device__ __forceinline__ float exp2_raw(float x) {
    float r;
    asm("v_exp_f32 %0, %1" : "=v"(r) : "v"(x));
    return r;
}

// ---------------------------------------------------------------------------
// FINAL CONFIG (session ledger):
//  - 3 dispatches. Fusion via threadfence (+53us, R6) and fence-free
//    ticket (+5us, R9) both regress; dispatch boundaries are cheap.
//  - K2 atomic epilogue: deterministic partials cost +18us (R1/R10).
//  - XCD swizzle null (R4: zi/zj L2-fit everywhere).
//  - Split staging / extra barriers regress (R7).
//  - Tile 128^2 == 256^2 (R13) and 8==16 waves/CU (R15/R16): K2 sits on
//    a latency/serialization floor (R16 @16 waves: VALUBusy 31%, Mfma 15%,
//    HBM 2%, no spill) -- not attackable by occupancy/tile/op-count.
//  - exp2_raw: the one proven op-count win (R16 probe).
// ---------------------------------------------------------------------------

// ---------------------------------------------------------------------------
// Kernel A: per row k, normalize emb_i[k] and emb_j[k] (fp32), write bf16
// z_i, z_j, pos[k] = cos-sim. One wave per row. Blocks 0..7 zero exactly
// the denom region (32 KB), race-free.
// ---------------------------------------------------------------------------
__global__ __launch_bounds__(256) void normalize_kernel(
    const float* __restrict__ emb_i, const float* __restrict__ emb_j,
    bf16_t* __restrict__ zi, bf16_t* __restrict__ zj, float* __restrict__ pos,
    float* __restrict__ denoms /* rowDenom(4096) ++ colDenom(4096) */)
{
    if (blockIdx.x < 8) {
        int idx = (blockIdx.x * 256 + threadIdx.x) * 4;
        *(float4*)&denoms[idx] = make_float4(0.f, 0.f, 0.f, 0.f);
    }

    int wave = threadIdx.x >> 6;
    int lane = threadIdx.x & 63;
    int k = blockIdx.x * 4 + wave;

    const float2* ei = (const float2*)(emb_i + (size_t)k * DIM);
    const float2* ej = (const float2*)(emb_j + (size_t)k * DIM);
    float2 a = ei[lane];
    float2 b = ej[lane];

    float sii = a.x * a.x + a.y * a.y;
    float sjj = b.x * b.x + b.y * b.y;
    float sij = a.x * b.x + a.y * b.y;
#pragma unroll
    for (int m = 1; m < 64; m <<= 1) {
        sii += __shfl_xor(sii, m);
        sjj += __shfl_xor(sjj, m);
        sij += __shfl_xor(sij, m);
    }
    float inv_i = 1.0f / fmaxf(sqrtf(sii), 1e-12f);
    float inv_j = 1.0f / fmaxf(sqrtf(sjj), 1e-12f);

    struct bf16_2 { bf16_t x, y; };
    bf16_2 pi, pj;
    pi.x = (bf16_t)(a.x * inv_i);  pi.y = (bf16_t)(a.y * inv_i);
    pj.x = (bf16_t)(b.x * inv_j);  pj.y = (bf16_t)(b.y * inv_j);
    ((bf16_2*)(zi + (size_t)k * DIM))[lane] = pi;
    ((bf16_2*)(zj + (size_t)k * DIM))[lane] = pj;

    if (lane == 0) pos[k] = sij * inv_i * inv_j;
}

// ---------------------------------------------------------------------------
// Kernel B: 128x128 tile of S = Zi * Zj^T per block (grid 32x32), 512
// threads = 8 waves in a 4x2 grid (each wave 32x64 out, acc[2][4]).
// launch_bounds(512,4): 128-VGPR cap, compiler allocates 64, no spill
// (R16 counters). Padded-136 LDS rows (free 2-way bank pattern). Epilogue:
// e = exp2_raw(EXP_SCALE*s); row sums 16-lane shfl + cross-wave LDS ->
// 1 atomic/row; col sums quad shfl + cross-wave LDS -> 1 atomic/col.
// ---------------------------------------------------------------------------
__global__ __launch_bounds__(512, 4) void gemm_exp_kernel(
    const bf16_t* __restrict__ zi, const bf16_t* __restrict__ zj,
    float* __restrict__ rowDenom, float* __restrict__ colDenom)
{
    __shared__ __align__(16) bf16_t zi_s[128][136];
    __shared__ __align__(16) bf16_t zj_s[128][136];
    __shared__ float rowRed[2][128];
    __shared__ float colRed[4][128];

    const int tid = threadIdx.x;
    const int ti = blockIdx.x, tj = blockIdx.y;

    // Stage 128x128 bf16 of each matrix: 2048 16B-chunks / matrix, 4 iters.
#pragma unroll
    for (int it = 0; it < 4; ++it) {
        int c = it * 512 + tid;
        int row = c >> 4;          // 16 chunks per row
        int col = (c & 15) << 3;   // 8 bf16 per chunk
        *(uint4*)&zi_s[row][col] =
            *(const uint4*)(zi + ((size_t)(ti * 128 + row)) * DIM + col);
        *(uint4*)&zj_s[row][col] =
            *(const uint4*)(zj + ((size_t)(tj * 128 + row)) * DIM + col);
    }
    __syncthreads();

    const int wave = tid >> 6;
    const int lane = tid & 63;
    const int l15  = lane & 15;
    const int quad = lane >> 4;
    const int wr   = wave >> 1;   // 0..3 : 32-row group
    const int wc   = wave & 1;    // 0..1 : 64-col group

    const f32x4 vzero = {0.f, 0.f, 0.f, 0.f};
    f32x4 acc[2][4];
#pragma unroll
    for (int mr = 0; mr < 2; ++mr)
#pragma unroll
        for (int nc = 0; nc < 4; ++nc) acc[mr][nc] = vzero;

#pragma unroll
    for (int ks = 0; ks < 4; ++ks) {
        int k0 = ks * 32 + quad * 8;
        bf16x8 afrag[2], bfrag[4];
#pragma unroll
        for (int mr = 0; mr < 2; ++mr)
            afrag[mr] = *(const bf16x8*)&zi_s[wr * 32 + mr * 16 + l15][k0];
#pragma unroll
        for (int nc = 0; nc < 4; ++nc)
            bfrag[nc] = *(const bf16x8*)&zj_s[wc * 64 + nc * 16 + l15][k0];
#pragma unroll
        for (int mr = 0; mr < 2; ++mr)
#pragma unroll
            for (int nc = 0; nc < 4; ++nc)
                acc[mr][nc] = __builtin_amdgcn_mfma_f32_16x16x32_bf16(
                    afrag[mr], bfrag[nc], acc[mr][nc], 0, 0, 0);
    }

    // Epilogue: exp and partial sums.
    // C/D layout: col = l15, row = quad*4 + r (within each 16x16 frag).
    float rowPart[2][4] = {{0.f, 0.f, 0.f, 0.f}, {0.f, 0.f, 0.f, 0.f}};
    float colPart[4]    = {0.f, 0.f, 0.f, 0.f};
#pragma unroll
    for (int mr = 0; mr < 2; ++mr)
#pragma unroll
        for (int nc = 0; nc < 4; ++nc)
#pragma unroll
            for (int r = 0; r < 4; ++r) {
                float e = exp2_raw(acc[mr][nc][r] * EXP_SCALE);
                rowPart[mr][r] += e;   // row = wr*32 + mr*16 + quad*4 + r
                colPart[nc]    += e;   // col = wc*64 + nc*16 + l15
            }

    // Row sums: 16-lane shfl completes this wave's 64 cols; cross-wave
    // (2 wc-groups) via LDS.
#pragma unroll
    for (int mr = 0; mr < 2; ++mr)
#pragma unroll
        for (int r = 0; r < 4; ++r) {
            float v = rowPart[mr][r];
            v += __shfl_xor(v, 1);
            v += __shfl_xor(v, 2);
            v += __shfl_xor(v, 4);
            v += __shfl_xor(v, 8);
            if (l15 == 0)
                rowRed[wc][wr * 32 + mr * 16 + quad * 4 + r] = v;
        }

    // Col sums: quad shfl-reduce completes this wave's 32 rows;
    // cross-wave (4 wr-groups) via LDS.
#pragma unroll
    for (int nc = 0; nc < 4; ++nc) {
        float v = colPart[nc];
        v += __shfl_xor(v, 16);
        v += __shfl_xor(v, 32);
        if (quad == 0) colRed[wr][wc * 64 + nc * 16 + l15] = v;
    }
    __syncthreads();

    if (tid < 128) {
        float rs = rowRed[0][tid] + rowRed[1][tid];
        atomicAdd(&rowDenom[ti * 128 + tid], rs);
    } else if (tid < 256) {
        int c = tid - 128;
        float cs = colRed[0][c] + colRed[1][c] + colRed[2][c] + colRed[3][c];
        atomicAdd(&colDenom[tj * 128 + c], cs);
    }
}

// ---------------------------------------------------------------------------
// Kernel C: 1 block x 1024 threads; 3 independent float4 loads per thread,
// 8 logf, wave shfl-reduce, 16-way LDS reduce.
// ---------------------------------------------------------------------------
__global__ __launch_bounds__(1024) void finalize_kernel(
    const float* __restrict__ denoms, const float* __restrict__ pos,
    float* __restrict__ out)
{
    const float4* rowD4 = (const float4*)denoms;            // 1024 float4
    const float4* colD4 = (const float4*)(denoms + BATCH);  // 1024 float4
    const float4* pos4  = (const float4*)pos;               // 1024 float4

    const int tid  = threadIdx.x;
    const int lane = tid & 63;
    const int wv   = tid >> 6;

    float4 rd = rowD4[tid];
    float4 cd = colD4[tid];
    float4 p  = pos4[tid];

    float acc = logf(rd.x) + logf(rd.y) + logf(rd.z) + logf(rd.w)
              + logf(cd.x) + logf(cd.y) + logf(cd.z) + logf(cd.w)
              - 8.0f * (p.x + p.y + p.z + p.w);

#pragma unroll
    for (int m = 1; m < 64; m <<= 1) acc += __shfl_xor(acc, m);

    __shared__ float red[16];
    if (lane == 0) red[wv] = acc;
    __syncthreads();
    if (wv == 0) {
        float v = (lane < 16) ? red[lane] : 0.0f;
#pragma unroll
        for (int m = 1; m < 64; m <<= 1) v += __shfl_xor(v, m);
        if (lane == 0) out[0] = v * (1.0f / (2.0f * BATCH));
    }
}

extern "C" void kernel_launch(void* const* d_in, const int* in_sizes, int n_in,
                              void* d_out, int out_size, void* d_ws, size_t ws_size,
                              hipStream_t stream) {
    const float* emb_i = (const float*)d_in[0];
    const float* emb_j = (const float*)d_in[1];
    float* out = (float*)d_out;

    char* ws = (char*)d_ws;
    bf16_t* zi     = (bf16_t*)(ws);                 // 1 MB
    bf16_t* zj     = (bf16_t*)(ws + (1u << 20));    // 1 MB
    float*  denoms = (float*)(ws + (2u << 20));     // 32 KB (row ++ col)
    float*  pos    = denoms + 2 * BATCH;            // 16 KB

    normalize_kernel<<<BATCH / 4, 256, 0, stream>>>(emb_i, emb_j, zi, zj, pos, denoms);
    gemm_exp_kernel<<<dim3(NT, NT), 512, 0, stream>>>(zi, zj, denoms, denoms + BATCH);
    finalize_kernel<<<1, 1024, 0, stream>>>(denoms, pos, out);
}